// Round 16
// baseline (409.653 us; speedup 1.0000x reference)
//
#include <hip/hip_runtime.h>
#include <hip/hip_bf16.h>

// R15: RESTRUCTURE. Seven phaseB micro-theories null (pinned ~41us, all pipes
// idle); scatter pinned ~45. Both existed only to build C[100000][64]
// (C[src][batch[dst]] += pw_h*ew). Replace records+replay with ONE barrier-free
// streaming kernel doing direct global f32 atomicAdd into C (fire-and-forget,
// memory-side RMW), + R12's measured-~10us convert (C -> ct + tg).
// Predict: agg 45-60us @ high occ, convert ~10, memset C +4 -> total ~205-215.
// If agg > 70us: atomics rate-worse than split pipeline -> revert R13.

#define N_NODES 100000
#define N_EDGES 1600000
#define N_HOPS 3
#define D_HID 256
#define N_GRAPHS 64

#define CHUNK 32
#define NCHUNK 3125          /* 100000/32 */
#define FG 512               /* fused grid */

#define NB 625               /* buckets for convert (160 nodes each) */
#define RB 160
#define NI4G 1200000         /* total int4 edge-groups = 3 hops * 400000 */
#define NI4H 400000
#define AGG_BLOCKS 2048
#define AGG_THREADS (AGG_BLOCKS * 256)

// ws layout (ws >= 256MiB):
//  [0, 12.8MB)        ct bf16 A-frag [NCHUNK][4][64][8]
//  [12.8MB, 38.4MB)   C f32 [N_NODES][64] = 25.6MB          (agg -> convert)
//    overlay: s_part bf16 [FG][64*256] = 16.8MB             (fused onward)
//  [38.4MB, 38.5MB)   batch_u8 [100000]
//  [40MB, ...)        tg_rep f32[64][64] | s_sum f32[16384] | w1p bf16[32768]
#define CT_OFF    0u
#define C_OFF     12800000u
#define SPART_OFF C_OFF
#define BU8_OFF   38400000u
#define SMALL_OFF 40000000u
#define TGR_OFF   SMALL_OFF              /* 64*64*4 = 16384 B */
#define SSUM_OFF  (SMALL_OFF + 32768u)
#define W1P_OFF   (SMALL_OFF + 131072u)

typedef __attribute__((ext_vector_type(4))) float f32x4;
typedef __attribute__((ext_vector_type(8))) short s16x8;
typedef __attribute__((ext_vector_type(4))) int i32x4;
typedef __attribute__((ext_vector_type(4))) float fv4;

__device__ __forceinline__ unsigned short f2bf_rne(float f) {
    union { float f; unsigned u; } v; v.f = f;
    unsigned r = v.u + 0x7FFFu + ((v.u >> 16) & 1u);
    return (unsigned short)(r >> 16);
}
__device__ __forceinline__ float bf2f(unsigned short s) {
    union { float f; unsigned u; } v; v.u = ((unsigned)s) << 16;
    return v.f;
}
__device__ __forceinline__ unsigned pk_rne(float lo, float hi) {
    return ((unsigned)f2bf_rne(hi) << 16) | (unsigned)f2bf_rne(lo);
}

// ---- Prep: blocks 0-15 pack W1 MFMA-B fragments; blocks 16-113 build u8 batch.
__global__ __launch_bounds__(256) void prep_kernel(const float* __restrict__ w1,
                                                   unsigned short* __restrict__ w1p,
                                                   const int* __restrict__ batch,
                                                   unsigned char* __restrict__ bu8) {
    if (blockIdx.x < 16) {
        int f = blockIdx.x * 256 + threadIdx.x;   // 0..4095
        int t = f >> 4, fr = f & 15, nt = fr >> 2, ks = fr & 3;
        int w = t >> 6, l = t & 63, q = l >> 4, c = l & 15;
        s16x8 v;
#pragma unroll
        for (int j = 0; j < 8; j++)
            v[j] = (short)f2bf_rne(w1[(size_t)(32 * ks + 8 * q + j) * 256 + w * 64 + 16 * nt + c]);
        *(s16x8*)&w1p[(size_t)f * 8] = v;
    } else {
        int i = (blockIdx.x - 16) * 1024 + threadIdx.x * 4;
        if (i < N_NODES) {
            int4 v = *(const int4*)&batch[i];
            uchar4 o;
            o.x = (unsigned char)v.x; o.y = (unsigned char)v.y;
            o.z = (unsigned char)v.z; o.w = (unsigned char)v.w;
            *(uchar4*)&bu8[i] = o;
        }
    }
}

// ---- Agg: barrier-free edge stream -> global f32 atomics into C.
// 2048 blocks x 256 threads = 8192 waves (full device), ~2.3 int4-groups each.
// NT vector loads for the edge stream; bu8 gather (100KB, L2-resident) for the
// graph id; atomicAdd without return = fire-and-forget memory-side RMW.
__global__ __launch_bounds__(256) void agg_kernel(
    const int* __restrict__ ei, const float* __restrict__ ew,
    const unsigned char* __restrict__ bu8, const float* __restrict__ pw,
    float* __restrict__ C) {
    const float pw1 = pw[1], pw2 = pw[2], pw3 = pw[3];
    int gid = blockIdx.x * 256 + threadIdx.x;
    for (int i4 = gid; i4 < NI4G; i4 += AGG_THREADS) {
        unsigned hop = (unsigned)i4 / NI4H;
        int r4 = i4 - (int)hop * NI4H;
        const i32x4* sp4 = (const i32x4*)(ei + (size_t)hop * 2 * N_EDGES);
        i32x4 s = __builtin_nontemporal_load(sp4 + r4);
        i32x4 d = __builtin_nontemporal_load(sp4 + NI4H + r4);
        fv4 wv = __builtin_nontemporal_load((const fv4*)(ew + (size_t)hop * N_EDGES) + r4);
        float pwh = hop == 0 ? pw1 : (hop == 1 ? pw2 : pw3);
#pragma unroll
        for (int j = 0; j < 4; j++) {
            unsigned g = bu8[d[j]];
            atomicAdd(&C[(size_t)(unsigned)s[j] * 64 + g], pwh * wv[j]);
        }
    }
}

// ---- Convert: one block per 160-node bucket. Coalesced C -> LDS tile,
// add pw0 at (n, batch[n]), emit ct (MFMA-A bf16 layout) + tg replicas
// (block b -> replica b&63). This is R12's B2 (~10us measured), reading C.
__global__ __launch_bounds__(512) void convert_kernel(
    const float* __restrict__ C, const unsigned char* __restrict__ bu8,
    const float* __restrict__ pw,
    unsigned short* __restrict__ ct, float* __restrict__ tgr) {
    __shared__ float tile[RB * 64];   // 40960 B
    const int tid = threadIdx.x;
    const int b = blockIdx.x;

    const f32x4* src = (const f32x4*)(C + (size_t)b * RB * 64);
    for (int i = tid; i < RB * 16; i += 512)
        *(f32x4*)&tile[i * 4] = src[i];
    __syncthreads();

    if (tid < RB) tile[tid * 64 + bu8[b * RB + tid]] += pw[0];
    __syncthreads();

    if (tid < 256) {
        const int gt = tid >> 6, l = tid & 63, q = l >> 4, c = l & 15;
        for (int cc = 0; cc < 5; cc++) {
            s16x8 v;
#pragma unroll
            for (int j = 0; j < 8; j++)
                v[j] = (short)f2bf_rne(tile[(cc * 32 + 8 * q + j) * 64 + 16 * gt + c]);
            *(s16x8*)&ct[(((size_t)(b * 5 + cc) * 4 + gt) * 64 + l) * 8] = v;
        }
    }
    if (tid < 64) {
        float sum = 0.f;
        for (int s = 0; s < RB; s++) sum += tile[s * 64 + tid];
        atomicAdd(&tgr[(b & 63) * 64 + tid], sum);
    }
}

// ---- Fused MFMA kernel: per 32-node chunk,
//   U = relu(X@W1 + b1)   (W1 frags from w1p, coalesced)
//   S += Ct^T @ U
__global__ __launch_bounds__(256, 2) void fused_kernel(
    const float* __restrict__ x,
    const unsigned short* __restrict__ w1p,
    const float* __restrict__ b1,
    const unsigned short* __restrict__ ct,
    unsigned short* __restrict__ s_part) {

    __shared__ __align__(16) unsigned short Ut[256 * 40];     // 20 KB
    __shared__ __align__(16) unsigned short x_lds[32 * 136];  // 8.7 KB
    __shared__ __align__(16) unsigned short ct_lds[2048];     // 4 KB

    const int tid = threadIdx.x;
    const int w = tid >> 6, l = tid & 63, q = l >> 4, c = l & 15;
    const int wcol = w * 64;
    const int sr = tid >> 3, sk = (tid & 7) * 16;

    // W1 B-fragments: pre-packed, 16 coalesced 16B loads
    s16x8 w1f[4][4];
    {
        const s16x8* wp = (const s16x8*)(w1p + (size_t)tid * 128);
#pragma unroll
        for (int nt = 0; nt < 4; nt++)
#pragma unroll
            for (int ks = 0; ks < 4; ks++)
                w1f[nt][ks] = wp[nt * 4 + ks];
    }

    float bias[4];
#pragma unroll
    for (int nt = 0; nt < 4; nt++) bias[nt] = b1[wcol + 16 * nt + c];

    f32x4 sacc[4][4];
#pragma unroll
    for (int gt = 0; gt < 4; gt++)
#pragma unroll
        for (int nt = 0; nt < 4; nt++) sacc[gt][nt] = (f32x4)0.f;

    uint4 xp0, xp1;
    s16x8 ctp;

#define PREF(CI)                                                              \
    {                                                                         \
        const float4* p = (const float4*)&x[(size_t)((CI) * 32 + sr) * 128 + sk]; \
        float4 v0 = p[0], v1 = p[1], v2 = p[2], v3 = p[3];                    \
        xp0.x = pk_rne(v0.x, v0.y); xp0.y = pk_rne(v0.z, v0.w);               \
        xp0.z = pk_rne(v1.x, v1.y); xp0.w = pk_rne(v1.z, v1.w);               \
        xp1.x = pk_rne(v2.x, v2.y); xp1.y = pk_rne(v2.z, v2.w);               \
        xp1.z = pk_rne(v3.x, v3.y); xp1.w = pk_rne(v3.z, v3.w);               \
        ctp = *(const s16x8*)&ct[(size_t)(CI) * 2048 + tid * 8];              \
    }

    int ci = blockIdx.x;
    if (ci < NCHUNK) PREF(ci);

    for (; ci < NCHUNK; ci += FG) {
        *(uint4*)&x_lds[sr * 136 + sk] = xp0;
        *(uint4*)&x_lds[sr * 136 + sk + 8] = xp1;
        *(s16x8*)&ct_lds[tid * 8] = ctp;
        __syncthreads();

        s16x8 af[2][4], ctf[4];
#pragma unroll
        for (int mt = 0; mt < 2; mt++)
#pragma unroll
            for (int ks = 0; ks < 4; ks++)
                af[mt][ks] = *(const s16x8*)&x_lds[(16 * mt + c) * 136 + 32 * ks + 8 * q];
#pragma unroll
        for (int gt = 0; gt < 4; gt++)
            ctf[gt] = *(const s16x8*)&ct_lds[(gt * 64 + l) * 8];
        __syncthreads();

        if (ci + FG < NCHUNK) PREF(ci + FG);

        f32x4 u[2][4];
#pragma unroll
        for (int mt = 0; mt < 2; mt++)
#pragma unroll
            for (int nt = 0; nt < 4; nt++) {
                f32x4 a; a[0] = a[1] = a[2] = a[3] = bias[nt];
                u[mt][nt] = a;
            }
#pragma unroll
        for (int ks = 0; ks < 4; ks++)
#pragma unroll
            for (int mt = 0; mt < 2; mt++)
#pragma unroll
                for (int nt = 0; nt < 4; nt++)
                    u[mt][nt] = __builtin_amdgcn_mfma_f32_16x16x32_bf16(
                        af[mt][ks], w1f[nt][ks], u[mt][nt], 0, 0, 0);

#pragma unroll
        for (int mt = 0; mt < 2; mt++)
#pragma unroll
            for (int nt = 0; nt < 4; nt++) {
                f32x4 v = u[mt][nt];
                uint2 d;
                d.x = pk_rne(fmaxf(v[0], 0.f), fmaxf(v[1], 0.f));
                d.y = pk_rne(fmaxf(v[2], 0.f), fmaxf(v[3], 0.f));
                *(uint2*)&Ut[(wcol + 16 * nt + c) * 40 + 16 * mt + 4 * q] = d;
            }

#pragma unroll
        for (int nt = 0; nt < 4; nt++) {
            s16x8 uf = *(const s16x8*)&Ut[(wcol + 16 * nt + c) * 40 + 8 * q];
#pragma unroll
            for (int gt = 0; gt < 4; gt++)
                sacc[gt][nt] = __builtin_amdgcn_mfma_f32_16x16x32_bf16(
                    ctf[gt], uf, sacc[gt][nt], 0, 0, 0);
        }
    }
#undef PREF

    unsigned short* my = s_part + (size_t)blockIdx.x * (64 * 256);
#pragma unroll
    for (int gt = 0; gt < 4; gt++)
#pragma unroll
        for (int nt = 0; nt < 4; nt++)
#pragma unroll
            for (int r = 0; r < 4; r++)
                my[(16 * gt + 4 * q + r) * 256 + wcol + 16 * nt + c] =
                    f2bf_rne(sacc[gt][nt][r]);
}

// 256 blocks: element range split 64-wide, FG dim split 4-way for parallelism
__global__ __launch_bounds__(256) void reduce_kernel(const unsigned short* __restrict__ s_part,
                                                     float* __restrict__ s_sum) {
    __shared__ float red[4][64];
    const int l = threadIdx.x & 63, p = threadIdx.x >> 6;
    const int e = blockIdx.x * 64 + l;
    float a0 = 0.f, a1 = 0.f, a2 = 0.f, a3 = 0.f;
    for (int b = p * (FG / 4); b < (p + 1) * (FG / 4); b += 4) {
        a0 += bf2f(s_part[(size_t)(b + 0) * 16384 + e]);
        a1 += bf2f(s_part[(size_t)(b + 1) * 16384 + e]);
        a2 += bf2f(s_part[(size_t)(b + 2) * 16384 + e]);
        a3 += bf2f(s_part[(size_t)(b + 3) * 16384 + e]);
    }
    red[p][l] = (a0 + a1) + (a2 + a3);
    __syncthreads();
    if (p == 0) s_sum[e] = (red[0][l] + red[1][l]) + (red[2][l] + red[3][l]);
}

__global__ void finalize_kernel(const float* __restrict__ s,
                                const float* __restrict__ tgr,
                                const float* __restrict__ w2,
                                const float* __restrict__ b2,
                                float* __restrict__ out) {
    __shared__ float red[128];
    __shared__ float tgs;
    const int g = blockIdx.x;
    const int f = threadIdx.x;

    // reduce the 64 tg replicas for this graph (wave 0)
    if (f < 64) {
        float v = tgr[f * 64 + g];
        for (int off = 32; off; off >>= 1) v += __shfl_down(v, off, 64);
        if (f == 0) tgs = v;
    }
    __syncthreads();

    float acc = tgs * b2[f];
    for (int k = 0; k < D_HID; k++)
        acc += s[(size_t)g * 256 + k] * w2[(size_t)k * 128 + f];

    red[f] = acc;
    __syncthreads();
    for (int off = 64; off > 0; off >>= 1) {
        if (f < off) red[f] = fmaxf(red[f], red[f + off]);
        __syncthreads();
    }
    float mx = red[0];
    __syncthreads();
    red[f] = expf(acc - mx);
    __syncthreads();
    for (int off = 64; off > 0; off >>= 1) {
        if (f < off) red[f] += red[f + off];
        __syncthreads();
    }
    float lse = logf(red[0]);
    out[(size_t)g * 128 + f] = acc - mx - lse;
}

extern "C" void kernel_launch(void* const* d_in, const int* in_sizes, int n_in,
                              void* d_out, int out_size, void* d_ws, size_t ws_size,
                              hipStream_t stream) {
    const float* x     = (const float*)d_in[0];
    const int*   ei    = (const int*)d_in[1];
    const float* ew    = (const float*)d_in[2];
    const int*   batch = (const int*)d_in[3];
    const float* w1    = (const float*)d_in[4];
    const float* b1    = (const float*)d_in[5];
    const float* w2    = (const float*)d_in[6];
    const float* b2    = (const float*)d_in[7];
    const float* pw    = (const float*)d_in[8];
    float* out = (float*)d_out;

    unsigned short* ctp     = (unsigned short*)((char*)d_ws + CT_OFF);
    float*          Cp      = (float*)((char*)d_ws + C_OFF);
    unsigned short* s_part  = (unsigned short*)((char*)d_ws + SPART_OFF);
    unsigned char*  bu8     = (unsigned char*)((char*)d_ws + BU8_OFF);
    float*          tgrp    = (float*)((char*)d_ws + TGR_OFF);
    float*          s_sum   = (float*)((char*)d_ws + SSUM_OFF);
    unsigned short* w1pp    = (unsigned short*)((char*)d_ws + W1P_OFF);

    hipMemsetAsync(tgrp, 0, 64 * 64 * sizeof(float), stream);
    hipMemsetAsync(Cp, 0, (size_t)N_NODES * 64 * sizeof(float), stream);

    prep_kernel<<<dim3(114), 256, 0, stream>>>(w1, w1pp, batch, bu8);
    agg_kernel<<<dim3(AGG_BLOCKS), 256, 0, stream>>>(ei, ew, bu8, pw, Cp);
    convert_kernel<<<dim3(NB), 512, 0, stream>>>(Cp, bu8, pw, ctp, tgrp);
    fused_kernel<<<dim3(FG), 256, 0, stream>>>(x, w1pp, b1, ctp, s_part);
    reduce_kernel<<<dim3(256), 256, 0, stream>>>(s_part, s_sum);
    finalize_kernel<<<dim3(64), 128, 0, stream>>>(s_sum, tgrp, w2, b2, out);
}